// Round 10
// baseline (17.161 us; speedup 1.0000x reference)
//
#include <hip/hip_runtime.h>

// One-sided Chamfer via MFMA: out[b][m] = min_n ||p_m - q_n||^2.
// B=2, N=M=8192, D=3, fp32 in/out.
//
// K0 (prep): build the MFMA A-fragment (ref) table ONCE in d_ws:
//   frag[b][t][l] (short8, 512 KB total) -- exactly R9's per-slice staging
//   math, hoisted out of the hot kernel (R9 re-converted each slice in 64
//   blocks => 2M redundant conversions ~ 43% of main-kernel VALU).
// K1 (main): block = 8 waves x 32 shared queries; wave w owns ref-tiles
//   [w*32, w*32+32) covering ALL of N => no ws partials, no reduce kernel,
//   no atomics. Each lane loads frag[t*64+lane] global->VGPR (coalesced
//   dwordx4, table is L2-resident; LDS pipe unused in the hot loop).
//   Per tile: 1 load + 1 mfma_32x32x16_bf16 + 8-op min3 tree.
//   Epilogue: shfl_xor(32) fold + 1KB LDS cross-wave merge + direct store.
//
// Validated MFMA math (R8/R9, absmax 0.00195 << 0.047):
//   A row (ref q):   k0..7  [qh.x,qh.y,qh.z, qh.x,qh.y,qh.z, ql.x,ql.y]
//                    k8..15 [ql.z, q2h, q2l, 0,0,0,0,0]
//   B col (query p): k0..7  [-2ph.x,-2ph.y,-2ph.z, -2pl.x,-2pl.y,-2pl.z,
//                            -2ph.x,-2ph.y]
//                    k8..15 [-2ph.z, 1, 1, 0,0,0,0,0]
//   acc = q2 - 2(ph.qh + pl.qh + ph.ql);  d2 = max(min(acc) + p2_f32, 0)
//   A/B: row|col = lane&31, k = (lane>>5)*8+i | C/D: col=lane&31,
//   row=(r&3)+8*(r>>2)+4*(lane>>5)  [m74/m101]

typedef __attribute__((ext_vector_type(8)))  short  short8;
typedef __attribute__((ext_vector_type(16))) float  f32x16;

constexpr int BB = 2;
constexpr int NN = 8192;
constexpr int MM = 8192;

constexpr int TILES = NN / 32;       // 256 ref-tiles per batch
constexpr int WPB   = 8;             // waves per block
constexpr int TPW   = TILES / WPB;   // 32 tiles per wave
constexpr int BQ    = WPB * 64;      // 512 threads per block

__device__ inline unsigned short f2bf(float f) {          // RNE fp32->bf16
    unsigned u = __float_as_uint(f);
    return (unsigned short)((u + 0x7FFFu + ((u >> 16) & 1u)) >> 16);
}
__device__ inline float bf2f(unsigned short h) {
    return __uint_as_float((unsigned)h << 16);
}

__global__ __launch_bounds__(256) void chamfer_prep_kernel(
    const float* __restrict__ input,   // [B, N, 3]
    short8* __restrict__ frag)         // [B, TILES, 64] in d_ws
{
    const int e = blockIdx.x * 256 + threadIdx.x;  // 0 .. 32767
    const int b = e >> 14;                         // TILES*64 = 16384
    const int r = e & 16383;
    const int t = r >> 6, l = r & 63;
    const int n = t * 32 + (l & 31);

    const float* inb = input + (size_t)b * NN * 3;
    const float x = inb[n * 3 + 0];
    const float y = inb[n * 3 + 1];
    const float z = inb[n * 3 + 2];
    const float q2 = fmaf(z, z, fmaf(y, y, x * x));
    const unsigned short hx = f2bf(x), hy = f2bf(y), hz = f2bf(z);
    const unsigned short lx = f2bf(x - bf2f(hx));
    const unsigned short ly = f2bf(y - bf2f(hy));
    const unsigned short lz = f2bf(z - bf2f(hz));
    const unsigned short q2h = f2bf(q2);
    const unsigned short q2l = f2bf(q2 - bf2f(q2h));
    short8 v;
    if ((l >> 5) == 0) {  // k0..7
        v[0] = (short)hx; v[1] = (short)hy; v[2] = (short)hz; v[3] = (short)hx;
        v[4] = (short)hy; v[5] = (short)hz; v[6] = (short)lx; v[7] = (short)ly;
    } else {              // k8..15
        v[0] = (short)lz; v[1] = (short)q2h; v[2] = (short)q2l; v[3] = 0;
        v[4] = 0; v[5] = 0; v[6] = 0; v[7] = 0;
    }
    frag[e] = v;
}

__global__ __launch_bounds__(BQ, 4) void chamfer_main_kernel(
    const short8* __restrict__ frag,   // [B, TILES, 64]
    const float* __restrict__ point,   // [B, M, 3]
    float* __restrict__ out)           // [B*M]
{
    __shared__ float pm[WPB][32];      // cross-wave partial minima

    const int tid  = threadIdx.x;
    const int lane = tid & 63;
    const int w    = tid >> 6;
    const int b    = blockIdx.y;
    const int qb0  = blockIdx.x * 32;

    // ---- B-fragment: this lane's query (col = lane&31) ----
    const int col = lane & 31, h = lane >> 5;
    const int m   = qb0 + col;
    const float* pp = point + ((size_t)b * MM + m) * 3;
    const float x = pp[0], y = pp[1], z = pp[2];
    const float p2 = fmaf(z, z, fmaf(y, y, x * x));
    const float hxf = bf2f(f2bf(x)), hyf = bf2f(f2bf(y)), hzf = bf2f(f2bf(z));
    const unsigned short bhx = f2bf(-2.0f * hxf);
    const unsigned short bhy = f2bf(-2.0f * hyf);
    const unsigned short bhz = f2bf(-2.0f * hzf);
    const unsigned short blx = f2bf(-2.0f * (x - hxf));
    const unsigned short bly = f2bf(-2.0f * (y - hyf));
    const unsigned short blz = f2bf(-2.0f * (z - hzf));
    const short one = (short)0x3F80;  // bf16 1.0
    short8 bq;
    if (h == 0) {
        bq[0] = (short)bhx; bq[1] = (short)bhy; bq[2] = (short)bhz; bq[3] = (short)blx;
        bq[4] = (short)bly; bq[5] = (short)blz; bq[6] = (short)bhx; bq[7] = (short)bhy;
    } else {
        bq[0] = (short)bhz; bq[1] = one; bq[2] = one; bq[3] = 0;
        bq[4] = 0; bq[5] = 0; bq[6] = 0; bq[7] = 0;
    }

    // ---- main loop: wave-private tile range, frag direct global->VGPR ----
    f32x16 zero;
#pragma unroll
    for (int i = 0; i < 16; ++i) zero[i] = 0.0f;
    float tmin = 3.0e38f;

    const short8* fw = frag + (size_t)b * (TILES * 64) + (size_t)w * TPW * 64;
#pragma unroll 4
    for (int t = 0; t < TPW; ++t) {
        const short8 af = fw[t * 64 + lane];
        const f32x16 d = __builtin_amdgcn_mfma_f32_32x32x16_bf16(af, bq, zero, 0, 0, 0);
        const float m0 = fminf(fminf(d[0],  d[1]),  d[2]);
        const float m1 = fminf(fminf(d[3],  d[4]),  d[5]);
        const float m2 = fminf(fminf(d[6],  d[7]),  d[8]);
        const float m3 = fminf(fminf(d[9],  d[10]), d[11]);
        const float m4 = fminf(fminf(d[12], d[13]), d[14]);
        const float r0 = fminf(fminf(m0, m1), d[15]);
        const float r1 = fminf(fminf(m2, m3), m4);
        tmin = fminf(fminf(tmin, r0), r1);
    }

    // ---- epilogue: fold row-halves, cross-wave LDS merge, direct store ----
    tmin = fminf(tmin, __shfl_xor(tmin, 32, 64));
    if (h == 0) pm[w][col] = tmin;
    __syncthreads();
    if (w == 0 && h == 0) {
        float v = pm[0][col];
#pragma unroll
        for (int r = 1; r < WPB; ++r) v = fminf(v, pm[r][col]);
        out[(size_t)b * MM + m] = fmaxf(v + p2, 0.0f);
    }
}

extern "C" void kernel_launch(void* const* d_in, const int* in_sizes, int n_in,
                              void* d_out, int out_size, void* d_ws, size_t ws_size,
                              hipStream_t stream) {
    const float* input = (const float*)d_in[0];   // [B, N, 3]
    const float* point = (const float*)d_in[1];   // [B, M, 3]
    float* out   = (float*)d_out;                 // [B, M]
    short8* frag = (short8*)d_ws;                 // 512 KB fragment table

    chamfer_prep_kernel<<<dim3(BB * TILES * 64 / 256), dim3(256), 0, stream>>>(input, frag);

    dim3 grid(MM / 32, BB);
    chamfer_main_kernel<<<grid, dim3(BQ), 0, stream>>>(frag, point, out);
}